// Round 3
// baseline (175.378 us; speedup 1.0000x reference)
//
#include <hip/hip_runtime.h>
#include <cstddef>

// Problem constants (bs=16, T=50, A=3, H=W=76, C=80, stride 8)
#define NB 16
#define NT 50
#define NA 3
#define NH 76
#define NW 76
#define NC 80
#define HWSZ (NH*NW)              // 5776
#define CPB 512                   // cells per block (2 per thread)
#define NBLKX ((HWSZ + CPB - 1) / CPB)   // 12
#define NBLK (NBLKX * NB * NA)    // 576

// scaled anchors = ANCHORS/8, scaled total = TOTAL/8
__constant__ float d_taw[9] = {1.25f,2.0f,4.125f,3.75f,7.75f,7.375f,14.5f,19.5f,46.625f};
__constant__ float d_tah[9] = {1.625f,3.75f,2.875f,7.625f,5.625f,14.875f,11.25f,24.75f,40.75f};
__constant__ float d_saw[3] = {1.25f,2.0f,4.125f};
__constant__ float d_sah[3] = {1.625f,3.75f,2.875f};

__device__ __forceinline__ float safelog(float p) {
    return p > 0.f ? logf(p) : -100.f;   // torch/jax BCE clamp
}
__device__ __forceinline__ float bce(float p, float t) {
    return -(t * safelog(p) + (1.f - t) * safelog(1.f - p));
}
__device__ __forceinline__ float sl1(float p, float t) {
    float d = fabsf(p - t);
    return d < 1.f ? 0.5f * d * d : d - 0.5f;
}
__device__ __forceinline__ float sigmoidf(float z) { return 1.f / (1.f + expf(-z)); }

// Per-cell loss terms for the rare masked path + noobj term.
// Match list is tiny (usually empty); loops over it are wave-uniform skips.
__device__ __forceinline__ void cell_terms(
    bool act, int loff, float x, float y, float zw, float zh, float zc,
    bool ignore, const float (*st)[16], int nm,
    const int* __restrict__ moff, const int* __restrict__ mt,
    const int* __restrict__ mcls, const float* __restrict__ clsbase,
    float* v /* 6 accumulators */)
{
    if (!act) return;
    int tl = -1;
    for (int e = 0; e < nm; e++)
        if (moff[e] == loff) tl = max(tl, mt[e]);      // last scatter wins
    float conf = sigmoidf(zc);
    if (tl >= 0) {
        unsigned long long m0 = 0ull; unsigned m1 = 0u; // tcls OR over all matches
        for (int e = 0; e < nm; e++)
            if (moff[e] == loff) {
                int c = mcls[e];
                if (c < 64) m0 |= 1ull << c; else m1 |= 1u << (c - 64);
            }
        const float* td = st[tl];
        float sc = td[8];
        v[0] += sc * bce(x, td[9]);
        v[1] += sc * bce(y, td[10]);
        v[2] += sc * sl1(zw, td[11]);
        v[3] += sc * sl1(zh, td[12]);
        v[4] += -safelog(conf);                         // bce(conf, 1)
        float lcls = 0.f;
        for (int c = 0; c < NC; c++) {
            float pc = sigmoidf(clsbase[(size_t)c * HWSZ]);
            float tc = ((c < 64) ? ((m0 >> c) & 1ull) : ((m1 >> (c - 64)) & 1u))
                           ? 1.f : 0.f;
            lcls += bce(pc, tc);
        }
        v[5] += lcls;
    } else if (!ignore) {
        v[4] += 0.5f * (-safelog(1.f - conf));          // 0.5 * bce(conf, 0)
    }
}

// ---------------- kernel 1: per-cell losses, block partials ----------------
__global__ __launch_bounds__(256) void k_main(const float* __restrict__ in,
                                              const float* __restrict__ tg,
                                              float* __restrict__ partials) {
    const int b = blockIdx.y / NA;
    const int a = blockIdx.y % NA;
    const int tid = threadIdx.x;
    const int base = blockIdx.x * CPB;

    // target records: [0..3]=x1,y1,x2,y2  [4]=area(+inf if invalid)
    //                 [8]=scales [9]=tx [10]=ty [11]=tw [12]=th
    __shared__ __align__(16) float st[NT][16];
    __shared__ int s_nm, s_moff[NT], s_mt[NT], s_mcls[NT];
    if (tid == 0) s_nm = 0;
    __syncthreads();
    if (tid < NT) {
        const float* tp = tg + ((size_t)b * NT + tid) * 5;
        float t0 = tp[0], t1 = tp[1], t2 = tp[2], t3 = tp[3], t4 = tp[4];
        bool valid = (t0 + t1 + t2 + t3 + t4) != 0.f;
        float gx = t1 * NW, gy = t2 * NH, gw = t3 * NW, gh = t4 * NH;
        int gi = (int)gx, gj = (int)gy;          // truncation; gx,gy >= 0
        // best of 9 total anchors; first-max wins, matching jnp.argmax
        float best = -1.f; int bn = 0;
        #pragma unroll
        for (int n = 0; n < 9; n++) {
            float inter = fminf(gw, d_taw[n]) * fminf(gh, d_tah[n]);
            float iou = inter / (gw * gh + d_taw[n] * d_tah[n] - inter + 1e-16f);
            if (iou > best) { best = iou; bn = n; }
        }
        int ai = (bn < NA) ? bn : -1;
        bool write = valid && (ai >= 0);
        int aic = (ai < 0) ? 0 : ai;
        float x1 = gx - gw * 0.5f, y1 = gy - gh * 0.5f;
        float x2 = gx + gw * 0.5f, y2 = gy + gh * 0.5f;
        float* o = st[tid];
        o[0] = x1; o[1] = y1; o[2] = x2; o[3] = y2;
        o[4] = valid ? (x2 - x1) * (y2 - y1) : __builtin_inff();
        o[8] = 2.f - t3 * t4;
        o[9] = gx - (float)gi; o[10] = gy - (float)gj;
        o[11] = logf(gw / d_saw[aic] + 1e-16f);
        o[12] = logf(gh / d_sah[aic] + 1e-16f);
        if (write && ai == a) {
            int off = gj * NW + gi - base;
            if (off >= 0 && off < CPB) {
                int slot = atomicAdd(&s_nm, 1);
                s_moff[slot] = off; s_mt[slot] = tid; s_mcls[slot] = (int)t0;
            }
        }
    }
    __syncthreads();

    // two cells per thread: local offsets tid and tid+256
    const int p1 = base + tid, p2 = base + 256 + tid;
    const bool act1 = p1 < HWSZ, act2 = p2 < HWSZ;
    const int q1 = act1 ? p1 : 0, q2 = act2 ? p2 : 0;
    const float* ib = in + (size_t)(b * 255 + a * 85) * HWSZ;

    float zx1 = ib[q1], zy1 = ib[HWSZ + q1], zw1 = ib[2 * HWSZ + q1],
          zh1 = ib[3 * HWSZ + q1], zc1 = ib[4 * HWSZ + q1];
    float zx2 = ib[q2], zy2 = ib[HWSZ + q2], zw2 = ib[2 * HWSZ + q2],
          zh2 = ib[3 * HWSZ + q2], zc2 = ib[4 * HWSZ + q2];

    const int j1 = q1 / NW, i1 = q1 - j1 * NW;
    const int j2 = q2 / NW, i2 = q2 - j2 * NW;
    float x_1 = sigmoidf(zx1), y_1 = sigmoidf(zy1);
    float x_2 = sigmoidf(zx2), y_2 = sigmoidf(zy2);
    float pbx1 = x_1 + (float)i1, pby1 = y_1 + (float)j1;
    float pbx2 = x_2 + (float)i2, pby2 = y_2 + (float)j2;
    float pbw1 = expf(zw1) * d_saw[a], pbh1 = expf(zh1) * d_sah[a];
    float pbw2 = expf(zw2) * d_saw[a], pbh2 = expf(zh2) * d_sah[a];
    float px1a = pbx1 - pbw1 * 0.5f, px1b = pbx1 + pbw1 * 0.5f;
    float py1a = pby1 - pbh1 * 0.5f, py1b = pby1 + pbh1 * 0.5f;
    float px2a = pbx2 - pbw2 * 0.5f, px2b = pbx2 + pbw2 * 0.5f;
    float py2a = pby2 - pbh2 * 0.5f, py2b = pby2 + pbh2 * 0.5f;
    float pa1 = (px1b - px1a) * (py1b - py1a);
    float pa2 = (px2b - px2a) * (py2b - py2a);

    // hot loop: ignore test only; records prefetched 5 at a time into regs
    bool ig1 = false, ig2 = false;
    for (int tb = 0; tb < NT; tb += 5) {
        float4 B[5]; float A_[5];
        #pragma unroll
        for (int u = 0; u < 5; u++) {
            B[u] = *(const float4*)&st[tb + u][0];
            A_[u] = st[tb + u][4];
        }
        #pragma unroll
        for (int u = 0; u < 5; u++) {
            float iw1 = fmaxf(fminf(B[u].z, px1b) - fmaxf(B[u].x, px1a), 0.f);
            float ih1 = fmaxf(fminf(B[u].w, py1b) - fmaxf(B[u].y, py1a), 0.f);
            // iou >= 0.5  <=>  3*inter >= area_t + area_p   (denominator > 0)
            if (3.f * (iw1 * ih1) >= A_[u] + pa1) ig1 = true;
            float iw2 = fmaxf(fminf(B[u].z, px2b) - fmaxf(B[u].x, px2a), 0.f);
            float ih2 = fmaxf(fminf(B[u].w, py2b) - fmaxf(B[u].y, py2a), 0.f);
            if (3.f * (iw2 * ih2) >= A_[u] + pa2) ig2 = true;
        }
    }

    float v[6] = {0.f, 0.f, 0.f, 0.f, 0.f, 0.f};
    const int nm = s_nm;
    cell_terms(act1, tid,       x_1, y_1, zw1, zh1, zc1, ig1, st, nm,
               s_moff, s_mt, s_mcls, ib + 5 * HWSZ + q1, v);
    cell_terms(act2, tid + 256, x_2, y_2, zw2, zh2, zc2, ig2, st, nm,
               s_moff, s_mt, s_mcls, ib + 5 * HWSZ + q2, v);

    // block reduction: wave64 shuffle -> LDS -> 6 plain stores (NO atomics)
    __shared__ float red[4][6];
    const int wid = tid >> 6, lane = tid & 63;
    #pragma unroll
    for (int k = 0; k < 6; k++) {
        float s = v[k];
        #pragma unroll
        for (int off = 32; off > 0; off >>= 1) s += __shfl_down(s, off);
        if (lane == 0) red[wid][k] = s;
    }
    __syncthreads();
    if (tid < 6) {
        const int blk = blockIdx.y * NBLKX + blockIdx.x;
        partials[(size_t)blk * 8 + tid] =
            red[0][tid] + red[1][tid] + red[2][tid] + red[3][tid];
    }
}

// ---------------- kernel 2: reduce partials + n_obj + finalize ----------------
__global__ __launch_bounds__(512) void k_final(const float* __restrict__ tg,
                                               const float* __restrict__ partials,
                                               float* __restrict__ out) {
    const int wid = threadIdx.x >> 6, lane = threadIdx.x & 63;
    __shared__ float rs[8];
    if (wid < 6) {
        float s = 0.f;
        for (int i = lane; i < NBLK; i += 64) s += partials[(size_t)i * 8 + wid];
        #pragma unroll
        for (int off = 32; off > 0; off >>= 1) s += __shfl_down(s, off);
        if (lane == 0) rs[wid] = s;
    } else if (wid == 6) {
        int c = 0;
        for (int i = lane; i < NB * NT; i += 64) {
            const float* tp = tg + (size_t)i * 5;
            if ((tp[0] + tp[1] + tp[2] + tp[3] + tp[4]) != 0.f) c++;
        }
        #pragma unroll
        for (int off = 32; off > 0; off >>= 1) c += __shfl_down(c, off);
        if (lane == 0) rs[6] = (float)c;
    }
    __syncthreads();
    if (threadIdx.x == 0) {
        float n = rs[6];
        float lx = rs[0] / n, ly = rs[1] / n, lw = rs[2] / n, lh = rs[3] / n;
        float lc = rs[4] / n, lcls = rs[5] / n;
        out[0] = 2.5f * (lx + ly) + 2.5f * (lw + lh) + lc + lcls;
        out[1] = lx; out[2] = ly; out[3] = lw; out[4] = lh; out[5] = lc; out[6] = lcls;
    }
}

extern "C" void kernel_launch(void* const* d_in, const int* in_sizes, int n_in,
                              void* d_out, int out_size, void* d_ws, size_t ws_size,
                              hipStream_t stream) {
    const float* input   = (const float*)d_in[0];   // [16,255,76,76] f32
    const float* targets = (const float*)d_in[1];   // [16,50,5] f32
    float* out = (float*)d_out;                     // 7 f32
    float* ws  = (float*)d_ws;                      // block partials: NBLK*8 floats

    dim3 grid(NBLKX, NB * NA);                      // (12, 48)
    k_main<<<grid, 256, 0, stream>>>(input, targets, ws);
    k_final<<<1, 512, 0, stream>>>(targets, ws, out);
}